// Round 2
// 651.567 us; speedup vs baseline: 1.0111x; 1.0111x over previous
//
#include <hip/hip_runtime.h>

// SMFNet: V = relu(X @ Wg.T), F = relu(X @ Wf.T), out[i] = F[i,0]*V[i] + F[i,1]*V[(i+1)%N]
// X: [N,128] f32, Wf/Wg: [2,128] f32, out: [N,2] f32.
//
// Memory-bound floor: 512 MB X read + 8 MB out write ~= 82 us @ 6.3 TB/s.
// v1 was ds-pipe bound: 20 shfl_xor (ds_swizzle) per row for the 32-lane
// butterfly. This version assigns each 8-lane group ONE output scalar
// (v0/v1/f0/f1) over the full 128-col row -> reduction is 3 shfl per 2 rows
// (13x fewer cross-lane ops). The 4 groups load identical addresses; the
// coalescer merges duplicates, so HBM traffic is unchanged.

constexpr int ROWS  = 64;   // rows owned per block
constexpr int BLOCK = 256;  // 4 waves; each 32-lane half handles one row/iter

__global__ __launch_bounds__(BLOCK) void smfnet_kernel(
    const float* __restrict__ X,
    const float* __restrict__ Wf,
    const float* __restrict__ Wg,
    float* __restrict__ out,
    int N)
{
    __shared__ float4 ldsv[ROWS + 2];   // per virtual row: (v0, v1, f0, f1)
    float* lds = (float*)ldsv;

    const int tid  = threadIdx.x;
    const int wave = tid >> 6;        // 0..3
    const int lane = tid & 63;
    const int half = lane >> 5;       // 0 or 1 (row select within wave)
    const int sub  = lane & 31;
    const int grp  = sub >> 3;        // 0..3 -> which output: v0, v1, f0, f1
    const int idx  = sub & 7;         // chunk index within the 8-lane group

    const int r0  = blockIdx.x * ROWS;
    const int num = min(ROWS, N - r0);   // rows this block owns

    // Each lane caches the weight chunks for ITS output row:
    // grp 0 -> Wg[0], 1 -> Wg[1], 2 -> Wf[0], 3 -> Wf[1].
    const float* Wsel = (grp < 2 ? Wg : Wf) + ((grp & 1) << 7);
    const float4 w0 = ((const float4*)Wsel)[idx];
    const float4 w1 = ((const float4*)Wsel)[idx +  8];
    const float4 w2 = ((const float4*)Wsel)[idx + 16];
    const float4 w3 = ((const float4*)Wsel)[idx + 24];

    // Virtual rows 0..num inclusive; vr==num is the next block's first row
    // (wraps to 0 for the last block) -- only V is consumed from it.
    // 8 rows per iteration (4 waves x 2 halves).
    #pragma unroll
    for (int t = 0; t < (ROWS / 8) + 1; ++t) {
        const int vr = t * 8 + wave * 2 + half;
        if (vr <= num) {
            int i = r0 + vr;
            if (i >= N) i -= N;                     // wraparound for roll(-1)
            const float4* Xi = (const float4*)(X + (size_t)i * 128);

            // Full-row dot for this lane's output; 4 groups read the same
            // addresses (broadcast-merged by the coalescer).
            const float4 x0 = Xi[idx];
            const float4 x1 = Xi[idx +  8];
            const float4 x2 = Xi[idx + 16];
            const float4 x3 = Xi[idx + 24];

            float s;
            s  = x0.x*w0.x + x0.y*w0.y + x0.z*w0.z + x0.w*w0.w;
            s += x1.x*w1.x + x1.y*w1.y + x1.z*w1.z + x1.w*w1.w;
            s += x2.x*w2.x + x2.y*w2.y + x2.z*w2.z + x2.w*w2.w;
            s += x3.x*w3.x + x3.y*w3.y + x3.z*w3.z + x3.w*w3.w;

            // 8-lane reduction (xor masks stay within the group; predicate is
            // uniform across the 32-lane half, so shuffles are safe).
            s += __shfl_xor(s, 1);
            s += __shfl_xor(s, 2);
            s += __shfl_xor(s, 4);

            if (idx == 0) lds[vr * 4 + grp] = fmaxf(s, 0.f);
        }
    }
    __syncthreads();

    // Epilogue: out[i] = F[i,0]*V[i] + F[i,1]*V[i+1]; coalesced float2 stores.
    if (tid < num) {
        const float4 cur = ldsv[tid];
        const float4 nxt = ldsv[tid + 1];
        const float o0 = cur.z * cur.x + cur.w * nxt.x;
        const float o1 = cur.z * cur.y + cur.w * nxt.y;
        ((float2*)out)[(size_t)(r0 + tid)] = make_float2(o0, o1);
    }
}

extern "C" void kernel_launch(void* const* d_in, const int* in_sizes, int n_in,
                              void* d_out, int out_size, void* d_ws, size_t ws_size,
                              hipStream_t stream) {
    const float* X  = (const float*)d_in[0];
    const float* Wf = (const float*)d_in[1];
    const float* Wg = (const float*)d_in[2];
    float* out = (float*)d_out;

    const int N = in_sizes[0] / 128;
    const int grid = (N + ROWS - 1) / ROWS;
    smfnet_kernel<<<grid, BLOCK, 0, stream>>>(X, Wf, Wg, out, N);
}